// Round 1
// baseline (16660.387 us; speedup 1.0000x reference)
//
#include <hip/hip_runtime.h>
#include <stdint.h>

// BiGRU scan, H=1024. Strategy:
//  1) gh = h0 @ Whh^T + bhh precomputed as one fp32 GEMM (both chains, both dirs).
//  2) Persistent dataflow scan: 171 blocks x 256 thr, Wih rows register-resident
//     (each wave owns 3 output elems = 9 rows, k split across 64 lanes).
//     Cross-block y exchange via tagged 64-bit agent-scope atomics (tag = step+1),
//     double-buffered by step parity. No grid barrier, no fences needed (tag and
//     value travel in one naturally-aligned 8B atom).

#define H   1024
#define HH  1025
#define N3  3075      // 3*HH
#define TQ  512
#define TP  4096
#define MTOT 4608     // TQ + TP rows in gh (q tokens first, then p tokens)
#define GTOT 2050     // 2 dirs * HH output elems per step

typedef unsigned long long ull;

__device__ __forceinline__ float sigm(float x) { return 1.f / (1.f + __expf(-x)); }

// ---------------------------------------------------------------------------
// gh GEMM: gh[dir][m][r] = sum_k h0[m][dir][k] * Whh_dir[r][k] + bhh_dir[r]
// m in [0,4608): m<512 -> chain q token m ; else chain p token m-512.
// 128x128 tile, k-tile 16, 8x8 per thread, fp32.
// ---------------------------------------------------------------------------
__global__ __launch_bounds__(256, 2) void gh_gemm(
    const float* __restrict__ eq, const float* __restrict__ ep,
    const float* __restrict__ fs, const float* __restrict__ fe,
    const float* __restrict__ Whh_f, const float* __restrict__ bhh_f,
    const float* __restrict__ Whh_b, const float* __restrict__ bhh_b,
    float* __restrict__ ghf, float* __restrict__ ghb)
{
    const int dir = blockIdx.z;
    const float* W  = dir ? Whh_b : Whh_f;
    const float* bh = dir ? bhh_b : bhh_f;
    float* gh = dir ? ghb : ghf;
    const int n0 = blockIdx.x * 128;
    const int m0 = blockIdx.y * 128;

    __shared__ float As[16][132];  // [k][m], pad 132 keeps float4 alignment + low conflicts
    __shared__ float Bs[16][132];  // [k][r]

    float acc[8][8];
#pragma unroll
    for (int i = 0; i < 8; i++)
#pragma unroll
        for (int j = 0; j < 8; j++) acc[i][j] = 0.f;

    const int tid = threadIdx.x;
    const int tx = tid & 15, ty = tid >> 4;

    for (int k0 = 0; k0 < HH; k0 += 16) {
        // A tile: 128 m x 16 k (scalar loads; h0 is a gather of e/fs/fe)
#pragma unroll
        for (int u = 0; u < 8; u++) {
            int lin = tid + 256 * u;       // 0..2047
            int k = lin & 15;
            int m = lin >> 4;
            int gm = m0 + m;               // < 4608 always (36*128)
            int gk = k0 + k;
            float v = 0.f;
            if (gk < HH) {
                bool isq = gm < TQ;
                const float* e = isq ? eq : ep;
                int t = isq ? gm : gm - TQ;
                if (dir == 0)            v = e[(size_t)t * 2048 + gk];
                else if (gk < 1023)      v = e[(size_t)t * 2048 + 1025 + gk];
                else if (!isq)           v = (gk == 1023) ? fs[t] : fe[t];
                // else chain q, gk in {1023,1024}: v = 0
            }
            As[k][m] = v;
        }
        // B tile: 128 r x 16 k
#pragma unroll
        for (int u = 0; u < 8; u++) {
            int lin = tid + 256 * u;
            int k = lin & 15;
            int r = lin >> 4;
            int gr = n0 + r, gk = k0 + k;
            Bs[k][r] = (gr < N3 && gk < HH) ? W[(size_t)gr * HH + gk] : 0.f;
        }
        __syncthreads();
#pragma unroll
        for (int kk = 0; kk < 16; kk++) {
            float4 a0 = *(const float4*)&As[kk][ty * 4];
            float4 a1 = *(const float4*)&As[kk][64 + ty * 4];
            float4 b0 = *(const float4*)&Bs[kk][tx * 4];
            float4 b1 = *(const float4*)&Bs[kk][64 + tx * 4];
            float a[8] = {a0.x, a0.y, a0.z, a0.w, a1.x, a1.y, a1.z, a1.w};
            float b[8] = {b0.x, b0.y, b0.z, b0.w, b1.x, b1.y, b1.z, b1.w};
#pragma unroll
            for (int i = 0; i < 8; i++)
#pragma unroll
                for (int j = 0; j < 8; j++) acc[i][j] += a[i] * b[j];
        }
        __syncthreads();
    }
#pragma unroll
    for (int i = 0; i < 8; i++) {
        int gm = m0 + ((i < 4) ? (ty * 4 + i) : (64 + ty * 4 + i - 4));
#pragma unroll
        for (int j = 0; j < 8; j++) {
            int gr = n0 + ((j < 4) ? (tx * 4 + j) : (64 + tx * 4 + j - 4));
            if (gr < N3) gh[(size_t)gm * N3 + gr] = acc[i][j] + bh[gr];
        }
    }
}

// ---------------------------------------------------------------------------
// Persistent scan. 171 blocks x 256 threads; wave w of block b owns output
// elems g = b*12 + w*3 + {0,1,2}, g in [0,2050): dir = g/1025, j = g%1025.
// Lane l of a wave holds Wih[row][4l + 256i + m] for i<4, m<4; x is broadcast
// via LDS so dot-product partials land lane-aligned; 64->1 via shfl_xor.
// ---------------------------------------------------------------------------
__global__ __launch_bounds__(256, 1) void bigru_scan(
    const float* __restrict__ eq, const float* __restrict__ ep,
    const float* __restrict__ fs, const float* __restrict__ fe,
    const float* __restrict__ Wih_f, const float* __restrict__ bih_f,
    const float* __restrict__ Wih_b, const float* __restrict__ bih_b,
    const float* __restrict__ ghf, const float* __restrict__ ghb,
    ull* __restrict__ comm,   // [chain p|q][slot 0|1][GTOT] tagged values
    float* __restrict__ out)  // h_q (512*2048) then h_p (4096*2048)
{
    __shared__ float xsh[2][2][1024];  // [parity][chain p=0,q=1][j]

    const int tid  = threadIdx.x;
    const int wave = tid >> 6;
    const int lane = tid & 63;
    const int gbase = blockIdx.x * 12 + wave * 3;

    // ---- register-resident weights ----
    float wreg[9][16];
    float breg[9];
    int   dre[3], je[3];
    bool  vale[3];
#pragma unroll
    for (int e = 0; e < 3; e++) {
        int g = gbase + e;
        bool v = (g < GTOT);
        int gc = v ? g : 0;
        int dir = gc / HH;
        int j = gc % HH;
        dre[e] = dir; je[e] = j; vale[e] = v;
        const float* Wih = dir ? Wih_b : Wih_f;
        const float* bih = dir ? bih_b : bih_f;
#pragma unroll
        for (int gate = 0; gate < 3; gate++) {
            const float* wr = Wih + (size_t)(gate * HH + j) * H;
#pragma unroll
            for (int i = 0; i < 4; i++) {
                float4 w4 = *(const float4*)(wr + i * 256 + lane * 4);
                wreg[e * 3 + gate][i * 4 + 0] = w4.x;
                wreg[e * 3 + gate][i * 4 + 1] = w4.y;
                wreg[e * 3 + gate][i * 4 + 2] = w4.z;
                wreg[e * 3 + gate][i * 4 + 3] = w4.w;
            }
            breg[e * 3 + gate] = bih[gate * HH + j];
        }
    }

    ull* commP = comm;
    ull* commQ = comm + 2 * GTOT;

    for (int t = 0; t < TP; t++) {
        const bool doq = (t < TQ);
        const int par = t & 1;

        // ---- prefetch gh + h0 (independent of y; in flight during poll) ----
        float ghp[9], ghq[9], h0p[3], h0q[3];
#pragma unroll
        for (int e = 0; e < 3; e++) {
            const float* gh = dre[e] ? ghb : ghf;
            const int j = je[e];
            size_t basep = (size_t)(TQ + t) * N3;
            ghp[e * 3 + 0] = gh[basep + 0 * HH + j];
            ghp[e * 3 + 1] = gh[basep + 1 * HH + j];
            ghp[e * 3 + 2] = gh[basep + 2 * HH + j];
            if (dre[e] == 0) h0p[e] = ep[(size_t)t * 2048 + j];
            else h0p[e] = (j < 1023) ? ep[(size_t)t * 2048 + 1025 + j]
                                     : ((j == 1023) ? fs[t] : fe[t]);
            if (doq) {
                size_t baseq = (size_t)t * N3;
                ghq[e * 3 + 0] = gh[baseq + 0 * HH + j];
                ghq[e * 3 + 1] = gh[baseq + 1 * HH + j];
                ghq[e * 3 + 2] = gh[baseq + 2 * HH + j];
                if (dre[e] == 0) h0q[e] = eq[(size_t)t * 2048 + j];
                else h0q[e] = (j < 1023) ? eq[(size_t)t * 2048 + 1025 + j] : 0.f;
            } else { ghq[e*3+0]=ghq[e*3+1]=ghq[e*3+2]=0.f; h0q[e]=0.f; }
        }

        // ---- gather y_{t-1} -> x (all 256 threads; 4 x-elems each) ----
        if (t == 0) {
#pragma unroll
            for (int u = 0; u < 4; u++) {
                int j = tid + 256 * u;
                xsh[par][0][j] = 0.f;
                xsh[par][1][j] = 0.f;
            }
        } else {
            const int slot = (t + 1) & 1;     // (t-1) % 2
            const unsigned tag = (unsigned)t; // y_{t-1} carries tag t
            ull* cp = commP + slot * GTOT;
            ull* cq = commQ + slot * GTOT;
            int idx[8];
#pragma unroll
            for (int u = 0; u < 4; u++) {
                int j = tid + 256 * u;
                idx[2 * u]     = j;                              // yf[j]
                idx[2 * u + 1] = (j == 0) ? 1024 : (1025 + j - 1); // yb[j-1] (or yf[1024])
            }
            ull vp[8], vq[8];
#pragma unroll
            for (int u = 0; u < 8; u++)
                vp[u] = __hip_atomic_load(&cp[idx[u]], __ATOMIC_RELAXED, __HIP_MEMORY_SCOPE_AGENT);
            if (doq) {
#pragma unroll
                for (int u = 0; u < 8; u++)
                    vq[u] = __hip_atomic_load(&cq[idx[u]], __ATOMIC_RELAXED, __HIP_MEMORY_SCOPE_AGENT);
            }
#pragma unroll
            for (int u = 0; u < 8; u++) {
                while ((unsigned)(vp[u] >> 32) != tag) {
                    __builtin_amdgcn_s_sleep(1);
                    vp[u] = __hip_atomic_load(&cp[idx[u]], __ATOMIC_RELAXED, __HIP_MEMORY_SCOPE_AGENT);
                }
            }
#pragma unroll
            for (int u = 0; u < 4; u++) {
                int j = tid + 256 * u;
                xsh[par][0][j] = __uint_as_float((unsigned)vp[2 * u]) +
                                 __uint_as_float((unsigned)vp[2 * u + 1]);
            }
            if (doq) {
#pragma unroll
                for (int u = 0; u < 8; u++) {
                    while ((unsigned)(vq[u] >> 32) != tag) {
                        __builtin_amdgcn_s_sleep(1);
                        vq[u] = __hip_atomic_load(&cq[idx[u]], __ATOMIC_RELAXED, __HIP_MEMORY_SCOPE_AGENT);
                    }
                }
#pragma unroll
                for (int u = 0; u < 4; u++) {
                    int j = tid + 256 * u;
                    xsh[par][1][j] = __uint_as_float((unsigned)vq[2 * u]) +
                                     __uint_as_float((unsigned)vq[2 * u + 1]);
                }
            }
        }
        __syncthreads();

        // ---- dot products: chain p ----
        float accp[9];
        {
            float x[16];
#pragma unroll
            for (int i = 0; i < 4; i++) {
                float4 x4 = *(const float4*)&xsh[par][0][i * 256 + lane * 4];
                x[i * 4 + 0] = x4.x; x[i * 4 + 1] = x4.y;
                x[i * 4 + 2] = x4.z; x[i * 4 + 3] = x4.w;
            }
#pragma unroll
            for (int r = 0; r < 9; r++) {
                float s = 0.f;
#pragma unroll
                for (int i = 0; i < 16; i++) s += wreg[r][i] * x[i];
                accp[r] = s;
            }
        }
#pragma unroll
        for (int r = 0; r < 9; r++) {
            float v = accp[r];
#pragma unroll
            for (int off = 32; off > 0; off >>= 1) v += __shfl_xor(v, off, 64);
            accp[r] = v + breg[r];
        }

        // ---- dot products: chain q ----
        float accq[9];
        if (doq) {
            float x[16];
#pragma unroll
            for (int i = 0; i < 4; i++) {
                float4 x4 = *(const float4*)&xsh[par][1][i * 256 + lane * 4];
                x[i * 4 + 0] = x4.x; x[i * 4 + 1] = x4.y;
                x[i * 4 + 2] = x4.z; x[i * 4 + 3] = x4.w;
            }
#pragma unroll
            for (int r = 0; r < 9; r++) {
                float s = 0.f;
#pragma unroll
                for (int i = 0; i < 16; i++) s += wreg[r][i] * x[i];
#pragma unroll
                for (int off = 32; off > 0; off >>= 1) s += __shfl_xor(s, off, 64);
                accq[r] = s + breg[r];
            }
        }

        // ---- gates + tagged publish + output store ----
        const ull tagout = ((ull)(unsigned)(t + 1)) << 32;
#pragma unroll
        for (int e = 0; e < 3; e++) {
            int g = gbase + e;
            {
                float r = sigm(accp[e * 3 + 0] + ghp[e * 3 + 0]);
                float z = sigm(accp[e * 3 + 1] + ghp[e * 3 + 1]);
                float n = tanhf(accp[e * 3 + 2] + r * ghp[e * 3 + 2]);
                float y = (1.f - z) * n + z * h0p[e];
                if (lane == 0 && vale[e]) {
                    ull pk = tagout | (ull)__float_as_uint(y);
                    __hip_atomic_store(&commP[(t & 1) * GTOT + g], pk,
                                       __ATOMIC_RELAXED, __HIP_MEMORY_SCOPE_AGENT);
                    if (je[e] < H)
                        out[(size_t)TQ * 2048 + (size_t)t * 2048 + dre[e] * H + je[e]] = y;
                }
            }
            if (doq) {
                float r = sigm(accq[e * 3 + 0] + ghq[e * 3 + 0]);
                float z = sigm(accq[e * 3 + 1] + ghq[e * 3 + 1]);
                float n = tanhf(accq[e * 3 + 2] + r * ghq[e * 3 + 2]);
                float y = (1.f - z) * n + z * h0q[e];
                if (lane == 0 && vale[e]) {
                    ull pk = tagout | (ull)__float_as_uint(y);
                    __hip_atomic_store(&commQ[(t & 1) * GTOT + g], pk,
                                       __ATOMIC_RELAXED, __HIP_MEMORY_SCOPE_AGENT);
                    if (je[e] < H)
                        out[(size_t)t * 2048 + dre[e] * H + je[e]] = y;
                }
            }
        }
    }
}

extern "C" void kernel_launch(void* const* d_in, const int* in_sizes, int n_in,
                              void* d_out, int out_size, void* d_ws, size_t ws_size,
                              hipStream_t stream) {
    const float* eq    = (const float*)d_in[0];
    const float* ep    = (const float*)d_in[1];
    const float* fs    = (const float*)d_in[2];
    const float* fe    = (const float*)d_in[3];
    const float* Wih_f = (const float*)d_in[4];
    const float* Whh_f = (const float*)d_in[5];
    const float* bih_f = (const float*)d_in[6];
    const float* bhh_f = (const float*)d_in[7];
    const float* Wih_b = (const float*)d_in[8];
    const float* Whh_b = (const float*)d_in[9];
    const float* bih_b = (const float*)d_in[10];
    const float* bhh_b = (const float*)d_in[11];
    float* out = (float*)d_out;

    const size_t ghElems = (size_t)MTOT * N3;  // 14,169,600 floats per dir
    float* ghf = (float*)d_ws;
    float* ghb = ghf + ghElems;
    size_t commOff = ((2 * ghElems * sizeof(float)) + 4095) & ~(size_t)4095;
    ull* comm = (ull*)((char*)d_ws + commOff);

    // tags are 1..4096; zero (and even the 0xAA poison) never matches, but be tidy
    hipMemsetAsync(comm, 0, (size_t)4 * GTOT * sizeof(ull), stream);

    dim3 ggrid((N3 + 127) / 128, MTOT / 128, 2);
    gh_gemm<<<ggrid, 256, 0, stream>>>(eq, ep, fs, fe, Whh_f, bhh_f, Whh_b, bhh_b, ghf, ghb);

    bigru_scan<<<dim3(171), dim3(256), 0, stream>>>(
        eq, ep, fs, fe, Wih_f, bih_f, Wih_b, bih_b, ghf, ghb, comm, out);
}

// Round 2
// 14586.580 us; speedup vs baseline: 1.1422x; 1.1422x over previous
//
#include <hip/hip_runtime.h>
#include <stdint.h>

// BiGRU scan, H=1024. Round 2:
//  - gh GEMM unchanged (fp32, ~0.8-1.4 ms; MFMA-ize later if it shows).
//  - Scan: poll loads issued FIRST each step (clean vmcnt queue); batch retry
//    rounds (1 LLC latency per round, p+q combined, no s_sleep); gh/h0
//    software-pipelined one step ahead via readfirstlane-scalarized loads
//    (lgkmcnt, decoupled from the vmcnt tag checks).

#define H   1024
#define HH  1025
#define N3  3075      // 3*HH
#define TQ  512
#define TP  4096
#define MTOT 4608     // TQ + TP rows in gh (q tokens first, then p tokens)
#define GTOT 2050     // 2 dirs * HH output elems per step
#define GH_ELEMS (MTOT * N3)   // 14,169,600 floats per dir

typedef unsigned long long ull;

__device__ __forceinline__ float sigm(float x) { return 1.f / (1.f + __expf(-x)); }
__device__ __forceinline__ float fast_tanh(float x) {
    float e = __expf(2.f * x);
    return (e - 1.f) / (e + 1.f);
}

// ---------------------------------------------------------------------------
// gh GEMM: gh[dir][m][r] = sum_k h0[m][dir][k] * Whh_dir[r][k] + bhh_dir[r]
// ---------------------------------------------------------------------------
__global__ __launch_bounds__(256, 2) void gh_gemm(
    const float* __restrict__ eq, const float* __restrict__ ep,
    const float* __restrict__ fs, const float* __restrict__ fe,
    const float* __restrict__ Whh_f, const float* __restrict__ bhh_f,
    const float* __restrict__ Whh_b, const float* __restrict__ bhh_b,
    float* __restrict__ ghf, float* __restrict__ ghb)
{
    const int dir = blockIdx.z;
    const float* W  = dir ? Whh_b : Whh_f;
    const float* bh = dir ? bhh_b : bhh_f;
    float* gh = dir ? ghb : ghf;
    const int n0 = blockIdx.x * 128;
    const int m0 = blockIdx.y * 128;

    __shared__ float As[16][132];
    __shared__ float Bs[16][132];

    float acc[8][8];
#pragma unroll
    for (int i = 0; i < 8; i++)
#pragma unroll
        for (int j = 0; j < 8; j++) acc[i][j] = 0.f;

    const int tid = threadIdx.x;
    const int tx = tid & 15, ty = tid >> 4;

    for (int k0 = 0; k0 < HH; k0 += 16) {
#pragma unroll
        for (int u = 0; u < 8; u++) {
            int lin = tid + 256 * u;
            int k = lin & 15;
            int m = lin >> 4;
            int gm = m0 + m;
            int gk = k0 + k;
            float v = 0.f;
            if (gk < HH) {
                bool isq = gm < TQ;
                const float* e = isq ? eq : ep;
                int t = isq ? gm : gm - TQ;
                if (dir == 0)            v = e[(size_t)t * 2048 + gk];
                else if (gk < 1023)      v = e[(size_t)t * 2048 + 1025 + gk];
                else if (!isq)           v = (gk == 1023) ? fs[t] : fe[t];
            }
            As[k][m] = v;
        }
#pragma unroll
        for (int u = 0; u < 8; u++) {
            int lin = tid + 256 * u;
            int k = lin & 15;
            int r = lin >> 4;
            int gr = n0 + r, gk = k0 + k;
            Bs[k][r] = (gr < N3 && gk < HH) ? W[(size_t)gr * HH + gk] : 0.f;
        }
        __syncthreads();
#pragma unroll
        for (int kk = 0; kk < 16; kk++) {
            float4 a0 = *(const float4*)&As[kk][ty * 4];
            float4 a1 = *(const float4*)&As[kk][64 + ty * 4];
            float4 b0 = *(const float4*)&Bs[kk][tx * 4];
            float4 b1 = *(const float4*)&Bs[kk][64 + tx * 4];
            float a[8] = {a0.x, a0.y, a0.z, a0.w, a1.x, a1.y, a1.z, a1.w};
            float b[8] = {b0.x, b0.y, b0.z, b0.w, b1.x, b1.y, b1.z, b1.w};
#pragma unroll
            for (int i = 0; i < 8; i++)
#pragma unroll
                for (int j = 0; j < 8; j++) acc[i][j] += a[i] * b[j];
        }
        __syncthreads();
    }
#pragma unroll
    for (int i = 0; i < 8; i++) {
        int gm = m0 + ((i < 4) ? (ty * 4 + i) : (64 + ty * 4 + i - 4));
#pragma unroll
        for (int j = 0; j < 8; j++) {
            int gr = n0 + ((j < 4) ? (tx * 4 + j) : (64 + tx * 4 + j - 4));
            if (gr < N3) gh[(size_t)gm * N3 + gr] = acc[i][j] + bh[gr];
        }
    }
}

// ---------------------------------------------------------------------------
// Persistent scan. 171 blocks x 256 threads; wave w of block b owns output
// elems g = b*12 + w*3 + {0,1,2}. Lane l holds Wih[row][4l + 256i + m].
// ---------------------------------------------------------------------------
__global__ __launch_bounds__(256, 1) void bigru_scan(
    const float* __restrict__ eq, const float* __restrict__ ep,
    const float* __restrict__ fs, const float* __restrict__ fe,
    const float* __restrict__ Wih_f, const float* __restrict__ bih_f,
    const float* __restrict__ Wih_b, const float* __restrict__ bih_b,
    const float* __restrict__ ghf, const float* __restrict__ ghb,
    ull* __restrict__ comm,   // [chain p|q][slot 0|1][GTOT] tagged values
    float* __restrict__ out)  // h_q (512*2048) then h_p (4096*2048)
{
    __shared__ float xsh[2][2][1024];  // [parity][chain p=0,q=1][j]

    const int tid  = threadIdx.x;
    const int wave = tid >> 6;
    const int lane = tid & 63;
    const int gbase = blockIdx.x * 12 + wave * 3;

    // ---- register-resident weights ----
    float wreg[9][16];
    float breg[9];
    int   dre[3], je[3];
    bool  vale[3];
#pragma unroll
    for (int e = 0; e < 3; e++) {
        int g = gbase + e;
        bool v = (g < GTOT);
        int gc = v ? g : 0;
        int dir = gc / HH;
        int j = gc % HH;
        dre[e] = dir; je[e] = j; vale[e] = v;
        const float* Wih = dir ? Wih_b : Wih_f;
        const float* bih = dir ? bih_b : bih_f;
#pragma unroll
        for (int gate = 0; gate < 3; gate++) {
            const float* wr = Wih + (size_t)(gate * HH + j) * H;
#pragma unroll
            for (int i = 0; i < 4; i++) {
                float4 w4 = *(const float4*)(wr + i * 256 + lane * 4);
                wreg[e * 3 + gate][i * 4 + 0] = w4.x;
                wreg[e * 3 + gate][i * 4 + 1] = w4.y;
                wreg[e * 3 + gate][i * 4 + 2] = w4.z;
                wreg[e * 3 + gate][i * 4 + 3] = w4.w;
            }
            breg[e * 3 + gate] = bih[gate * HH + j];
        }
    }

    // ---- scalarized (wave-uniform) per-e offsets for the gh/h0 pipeline ----
    int sgh[3], sh0[3], sspec[3];
#pragma unroll
    for (int e = 0; e < 3; e++) {
        sgh[e]   = __builtin_amdgcn_readfirstlane(dre[e] * GH_ELEMS + je[e]);
        sh0[e]   = __builtin_amdgcn_readfirstlane(dre[e] ? (1025 + je[e]) : je[e]);
        sspec[e] = __builtin_amdgcn_readfirstlane(
                       (dre[e] && je[e] >= 1023) ? (je[e] - 1022) : 0);
    }
    const float* ghAll = ghf;  // ghb is contiguous at ghf + GH_ELEMS

    // ---- gh/h0 register pipeline (one step ahead) ----
    float ghcP[9], h0cP[3], ghcQ[9], h0cQ[3];

    auto loadP = [&](int tt, float gh9[9], float h03[3]) {
        size_t base = (size_t)(TQ + tt) * N3;
#pragma unroll
        for (int e = 0; e < 3; e++) {
#pragma unroll
            for (int gate = 0; gate < 3; gate++)
                gh9[e * 3 + gate] = ghAll[base + (size_t)sgh[e] + gate * HH];
            h03[e] = (sspec[e] == 0) ? ep[(size_t)tt * 2048 + sh0[e]]
                   : (sspec[e] == 1) ? fs[tt] : fe[tt];
        }
    };
    auto loadQ = [&](int tt, float gh9[9], float h03[3]) {
        size_t base = (size_t)tt * N3;
#pragma unroll
        for (int e = 0; e < 3; e++) {
#pragma unroll
            for (int gate = 0; gate < 3; gate++)
                gh9[e * 3 + gate] = ghAll[base + (size_t)sgh[e] + gate * HH];
            h03[e] = (sspec[e] == 0) ? eq[(size_t)tt * 2048 + sh0[e]] : 0.f;
        }
    };

    loadP(0, ghcP, h0cP);
    loadQ(0, ghcQ, h0cQ);

    ull* commP = comm;
    ull* commQ = comm + 2 * GTOT;

    for (int t = 0; t < TP; t++) {
        const bool doq = (t < TQ);
        const int par = t & 1;

        // ================= gather y_{t-1} -> x (polls FIRST) ================
        if (t == 0) {
#pragma unroll
            for (int u = 0; u < 4; u++) {
                int j = tid + 256 * u;
                xsh[par][0][j] = 0.f;
                xsh[par][1][j] = 0.f;
            }
        } else {
            const int slot = (t + 1) & 1;     // (t-1) % 2
            const unsigned tag = (unsigned)t; // y_{t-1} carries tag t
            ull* cp = commP + slot * GTOT;
            ull* cq = commQ + slot * GTOT;
            int idx[8];
#pragma unroll
            for (int u = 0; u < 4; u++) {
                int j = tid + 256 * u;
                idx[2 * u]     = j;                                // yf[j]
                idx[2 * u + 1] = (j == 0) ? 1024 : (1025 + j - 1); // yb[j-1]
            }
            ull vp[8], vq[8];
#pragma unroll
            for (int u = 0; u < 8; u++)
                vp[u] = __hip_atomic_load(&cp[idx[u]], __ATOMIC_RELAXED, __HIP_MEMORY_SCOPE_AGENT);
            if (doq) {
#pragma unroll
                for (int u = 0; u < 8; u++)
                    vq[u] = __hip_atomic_load(&cq[idx[u]], __ATOMIC_RELAXED, __HIP_MEMORY_SCOPE_AGENT);
            }
            // batch retry: one LLC latency per round, p+q overlapped
            bool done = false;
            while (!done) {
                done = true;
#pragma unroll
                for (int u = 0; u < 8; u++) {
                    if ((unsigned)(vp[u] >> 32) != tag) {
                        done = false;
                        vp[u] = __hip_atomic_load(&cp[idx[u]], __ATOMIC_RELAXED, __HIP_MEMORY_SCOPE_AGENT);
                    }
                }
                if (doq) {
#pragma unroll
                    for (int u = 0; u < 8; u++) {
                        if ((unsigned)(vq[u] >> 32) != tag) {
                            done = false;
                            vq[u] = __hip_atomic_load(&cq[idx[u]], __ATOMIC_RELAXED, __HIP_MEMORY_SCOPE_AGENT);
                        }
                    }
                }
            }
#pragma unroll
            for (int u = 0; u < 4; u++) {
                int j = tid + 256 * u;
                xsh[par][0][j] = __uint_as_float((unsigned)vp[2 * u]) +
                                 __uint_as_float((unsigned)vp[2 * u + 1]);
            }
            if (doq) {
#pragma unroll
                for (int u = 0; u < 4; u++) {
                    int j = tid + 256 * u;
                    xsh[par][1][j] = __uint_as_float((unsigned)vq[2 * u]) +
                                     __uint_as_float((unsigned)vq[2 * u + 1]);
                }
            }
        }
        __syncthreads();

        // ====== prefetch gh/h0 for t+1 (scalar path; hidden under dots) =====
        float ghnP[9], h0nP[3], ghnQ[9], h0nQ[3];
        const bool ldn = (t + 1) < TP;
        const bool ldq = (t + 1) < TQ;
        if (ldn) loadP(t + 1, ghnP, h0nP);
        if (ldq) loadQ(t + 1, ghnQ, h0nQ);

        // ========================= dot products =============================
        float accp[9];
        {
            float x[16];
#pragma unroll
            for (int i = 0; i < 4; i++) {
                float4 x4 = *(const float4*)&xsh[par][0][i * 256 + lane * 4];
                x[i * 4 + 0] = x4.x; x[i * 4 + 1] = x4.y;
                x[i * 4 + 2] = x4.z; x[i * 4 + 3] = x4.w;
            }
#pragma unroll
            for (int r = 0; r < 9; r++) {
                float s = 0.f;
#pragma unroll
                for (int i = 0; i < 16; i++) s += wreg[r][i] * x[i];
                accp[r] = s;
            }
        }
#pragma unroll
        for (int r = 0; r < 9; r++) {
            float v = accp[r];
#pragma unroll
            for (int off = 32; off > 0; off >>= 1) v += __shfl_xor(v, off, 64);
            accp[r] = v + breg[r];
        }

        float accq[9];
        if (doq) {
            float x[16];
#pragma unroll
            for (int i = 0; i < 4; i++) {
                float4 x4 = *(const float4*)&xsh[par][1][i * 256 + lane * 4];
                x[i * 4 + 0] = x4.x; x[i * 4 + 1] = x4.y;
                x[i * 4 + 2] = x4.z; x[i * 4 + 3] = x4.w;
            }
#pragma unroll
            for (int r = 0; r < 9; r++) {
                float s = 0.f;
#pragma unroll
                for (int i = 0; i < 16; i++) s += wreg[r][i] * x[i];
#pragma unroll
                for (int off = 32; off > 0; off >>= 1) s += __shfl_xor(s, off, 64);
                accq[r] = s + breg[r];
            }
        }

        // ================ gates; publish comm FIRST, out after ==============
        const ull tagout = ((ull)(unsigned)(t + 1)) << 32;
        float yP[3], yQ[3];
#pragma unroll
        for (int e = 0; e < 3; e++) {
            float r = sigm(accp[e * 3 + 0] + ghcP[e * 3 + 0]);
            float z = sigm(accp[e * 3 + 1] + ghcP[e * 3 + 1]);
            float n = fast_tanh(accp[e * 3 + 2] + r * ghcP[e * 3 + 2]);
            yP[e] = (1.f - z) * n + z * h0cP[e];
            if (lane == 0 && vale[e]) {
                ull pk = tagout | (ull)__float_as_uint(yP[e]);
                __hip_atomic_store(&commP[par * GTOT + (gbase + e)], pk,
                                   __ATOMIC_RELAXED, __HIP_MEMORY_SCOPE_AGENT);
            }
        }
        if (doq) {
#pragma unroll
            for (int e = 0; e < 3; e++) {
                float r = sigm(accq[e * 3 + 0] + ghcQ[e * 3 + 0]);
                float z = sigm(accq[e * 3 + 1] + ghcQ[e * 3 + 1]);
                float n = fast_tanh(accq[e * 3 + 2] + r * ghcQ[e * 3 + 2]);
                yQ[e] = (1.f - z) * n + z * h0cQ[e];
                if (lane == 0 && vale[e]) {
                    ull pk = tagout | (ull)__float_as_uint(yQ[e]);
                    __hip_atomic_store(&commQ[par * GTOT + (gbase + e)], pk,
                                       __ATOMIC_RELAXED, __HIP_MEMORY_SCOPE_AGENT);
                }
            }
        }
        // out stores (off the critical path)
        if (lane == 0) {
#pragma unroll
            for (int e = 0; e < 3; e++) {
                if (vale[e] && je[e] < H) {
                    out[(size_t)TQ * 2048 + (size_t)t * 2048 + dre[e] * H + je[e]] = yP[e];
                    if (doq)
                        out[(size_t)t * 2048 + dre[e] * H + je[e]] = yQ[e];
                }
            }
        }

        // rotate pipeline registers
        if (ldn) {
#pragma unroll
            for (int i = 0; i < 9; i++) ghcP[i] = ghnP[i];
#pragma unroll
            for (int e = 0; e < 3; e++) h0cP[e] = h0nP[e];
        }
        if (ldq) {
#pragma unroll
            for (int i = 0; i < 9; i++) ghcQ[i] = ghnQ[i];
#pragma unroll
            for (int e = 0; e < 3; e++) h0cQ[e] = h0nQ[e];
        }
    }
}

extern "C" void kernel_launch(void* const* d_in, const int* in_sizes, int n_in,
                              void* d_out, int out_size, void* d_ws, size_t ws_size,
                              hipStream_t stream) {
    const float* eq    = (const float*)d_in[0];
    const float* ep    = (const float*)d_in[1];
    const float* fs    = (const float*)d_in[2];
    const float* fe    = (const float*)d_in[3];
    const float* Wih_f = (const float*)d_in[4];
    const float* Whh_f = (const float*)d_in[5];
    const float* bih_f = (const float*)d_in[6];
    const float* bhh_f = (const float*)d_in[7];
    const float* Wih_b = (const float*)d_in[8];
    const float* Whh_b = (const float*)d_in[9];
    const float* bih_b = (const float*)d_in[10];
    const float* bhh_b = (const float*)d_in[11];
    float* out = (float*)d_out;

    const size_t ghElems = (size_t)GH_ELEMS;
    float* ghf = (float*)d_ws;
    float* ghb = ghf + ghElems;
    size_t commOff = ((2 * ghElems * sizeof(float)) + 4095) & ~(size_t)4095;
    ull* comm = (ull*)((char*)d_ws + commOff);

    hipMemsetAsync(comm, 0, (size_t)4 * GTOT * sizeof(ull), stream);

    dim3 ggrid((N3 + 127) / 128, MTOT / 128, 2);
    gh_gemm<<<ggrid, 256, 0, stream>>>(eq, ep, fs, fe, Whh_f, bhh_f, Whh_b, bhh_b, ghf, ghb);

    bigru_scan<<<dim3(171), dim3(256), 0, stream>>>(
        eq, ep, fs, fe, Wih_f, bih_f, Wih_b, bih_b, ghf, ghb, comm, out);
}